// Round 1
// baseline (137.894 us; speedup 1.0000x reference)
//
#include <hip/hip_runtime.h>

// Problem constants (match reference)
#define BB 32
#define TT 200
#define RR 4096
#define CC 81
#define IOU_THRESH 0.7f
#define RED 16.0f

// ws layout: [0]=npos, [1]=sum_ce, [2]=sum_acc, [3]=sum_reg
__global__ __launch_bounds__(256) void rcnn_main_kernel(
    const float* __restrict__ nms_reg,   // [B,R,4]
    const float* __restrict__ rcnn_reg,  // [B,R,4]
    const float* __restrict__ rcnn_cls,  // [B,R,C]
    const float* __restrict__ bboxes,    // [B,T,4]
    const int*   __restrict__ classes,   // [B,T]
    float* __restrict__ ws)
{
    __shared__ float s_box[TT * 4];
    __shared__ int   s_cls[TT];
    __shared__ float s_red[4][4];   // [wave][component]

    const int tid = threadIdx.x;
    const int blocks_per_b = RR / 256;                  // 16
    const int b = blockIdx.x / blocks_per_b;
    const int r = (blockIdx.x % blocks_per_b) * 256 + tid;

    // Stage this batch's GT boxes + classes into LDS
    for (int i = tid; i < TT * 4; i += 256) s_box[i] = bboxes[(long)b * TT * 4 + i];
    for (int i = tid; i < TT;     i += 256) s_cls[i] = classes[(long)b * TT + i];
    __syncthreads();

    // Proposal box
    const float4 a = *(const float4*)&nms_reg[((long)b * RR + r) * 4];
    const float area_a = (a.z - a.x) * (a.w - a.y);

    // argmax IoU over T (first-occurrence tie-break via strict >)
    float best_iou = -1.0f;
    int   best_t   = 0;
    #pragma unroll 4
    for (int t = 0; t < TT; ++t) {
        const float gt = s_box[t * 4 + 0];
        const float gl = s_box[t * 4 + 1];
        const float gb = s_box[t * 4 + 2];
        const float gr = s_box[t * 4 + 3];
        const float it = fmaxf(a.x, gt);
        const float il = fmaxf(a.y, gl);
        const float ib = fminf(a.z, gb);
        const float ir = fminf(a.w, gr);
        const float inter = fmaxf(ib - it, 0.0f) * fmaxf(ir - il, 0.0f);
        const float area_b = (gb - gt) * (gr - gl);
        const float iou = inter / (area_a + area_b - inter);
        if (iou > best_iou) { best_iou = iou; best_t = t; }
    }

    float pos = 0.0f, ce = 0.0f, acc = 0.0f, reg = 0.0f;
    if (best_iou > IOU_THRESH) {
        pos = 1.0f;

        // ---- regression target + SmoothL1 (summed over 4 coords) ----
        const float gt = s_box[best_t * 4 + 0];
        const float gl = s_box[best_t * 4 + 1];
        const float gb = s_box[best_t * 4 + 2];
        const float gr = s_box[best_t * 4 + 3];
        const float rt = rintf(gt / RED) * RED;   // rintf = round-half-even, matches jnp.round
        const float rl = rintf(gl / RED) * RED;
        const float rb = rintf(gb / RED) * RED;
        const float rr = rintf(gr / RED) * RED;
        float h = rb - rt; if (h == 0.0f) h = 1.0f;
        float w = rr - rl; if (w == 0.0f) w = 1.0f;
        const float t0 = (gt - rt) / h;
        const float t1 = (gl - rl) / w;
        const float t2 = (gb - rb) / h;
        const float t3 = (gr - rr) / w;

        const float4 p = *(const float4*)&rcnn_reg[((long)b * RR + r) * 4];
        const float d0 = fabsf(p.x - t0);
        const float d1 = fabsf(p.y - t1);
        const float d2 = fabsf(p.z - t2);
        const float d3 = fabsf(p.w - t3);
        reg  = (d0 < 1.0f) ? 0.5f * d0 * d0 : d0 - 0.5f;
        reg += (d1 < 1.0f) ? 0.5f * d1 * d1 : d1 - 0.5f;
        reg += (d2 < 1.0f) ? 0.5f * d2 * d2 : d2 - 0.5f;
        reg += (d3 < 1.0f) ? 0.5f * d3 * d3 : d3 - 0.5f;

        // ---- CE + accuracy over C=81 (only positives read rcnn_cls) ----
        const float* row = &rcnn_cls[((long)b * RR + r) * CC];
        const int cls = s_cls[best_t];
        float m = -INFINITY;
        int amax = 0;
        for (int c = 0; c < CC; ++c) {
            const float x = row[c];
            if (x > m) { m = x; amax = c; }   // strict > -> first max, matches jnp.argmax
        }
        float s = 0.0f;
        for (int c = 0; c < CC; ++c) s += expf(row[c] - m);
        ce  = m + logf(s) - row[cls];
        acc = (amax == cls) ? 1.0f : 0.0f;
    }

    // ---- wave (64-lane) shuffle reduction ----
    #pragma unroll
    for (int off = 32; off > 0; off >>= 1) {
        pos += __shfl_down(pos, off);
        ce  += __shfl_down(ce,  off);
        acc += __shfl_down(acc, off);
        reg += __shfl_down(reg, off);
    }
    const int wave = tid >> 6;
    const int lane = tid & 63;
    if (lane == 0) {
        s_red[wave][0] = pos;
        s_red[wave][1] = ce;
        s_red[wave][2] = acc;
        s_red[wave][3] = reg;
    }
    __syncthreads();
    if (tid == 0) {
        float P = 0.0f, E = 0.0f, A = 0.0f, G = 0.0f;
        #pragma unroll
        for (int v = 0; v < 4; ++v) {
            P += s_red[v][0];
            E += s_red[v][1];
            A += s_red[v][2];
            G += s_red[v][3];
        }
        atomicAdd(&ws[0], P);
        atomicAdd(&ws[1], E);
        atomicAdd(&ws[2], A);
        atomicAdd(&ws[3], G);
    }
}

__global__ void rcnn_final_kernel(const float* __restrict__ ws, float* __restrict__ out)
{
    const float npos  = ws[0];
    const float denom = fmaxf(npos, 1.0f);
    const bool  hp    = npos > 0.0f;
    out[0] = hp ? ws[1] / denom : 0.0f;   // cls_loss
    out[1] = hp ? ws[3] / denom : 0.0f;   // reg_loss
    out[2] = hp ? ws[2] / denom : 0.0f;   // acc
}

extern "C" void kernel_launch(void* const* d_in, const int* in_sizes, int n_in,
                              void* d_out, int out_size, void* d_ws, size_t ws_size,
                              hipStream_t stream) {
    const float* nms_reg  = (const float*)d_in[0];
    // d_in[1] = nms_cls, unused by forward
    const float* rcnn_reg = (const float*)d_in[2];
    const float* rcnn_cls = (const float*)d_in[3];
    const float* bboxes   = (const float*)d_in[4];
    const int*   classes  = (const int*)d_in[5];
    float* ws  = (float*)d_ws;
    float* out = (float*)d_out;

    hipMemsetAsync(ws, 0, 4 * sizeof(float), stream);
    rcnn_main_kernel<<<BB * (RR / 256), 256, 0, stream>>>(
        nms_reg, rcnn_reg, rcnn_cls, bboxes, classes, ws);
    rcnn_final_kernel<<<1, 1, 0, stream>>>(ws, out);
}